// Round 2
// baseline (103.606 us; speedup 1.0000x reference)
//
#include <hip/hip_runtime.h>
#include <hip/hip_bf16.h>

// Fused single-kernel: h = emb[:, :256] @ W_enc + b_enc ; LayerNorm*gamma+beta ; ReLU
// (topology branch of the reference is a provable no-op: pooled == embeddings)
//
// Round 5 (diagnostic + lean): rounds 3 and 4 — structurally very different —
// both timed 102.5-103.0 us, and rocprof top-5 bounds our kernels < 42 us each,
// while the BW roofline puts topo_mfma at ~10-12 us. Hypothesis: dur_us is
// dominated by fixed per-iteration overhead outside kernel bodies. This round
// minimizes the enqueued path to ONE kernel with ZERO workspace: W is packed
// f32->bf16 in-kernel per chunk (W_enc is 512 KB, L2-resident; pack uses
// v_cvt_pk_bf16_f32 via __float22bfloat162_rn, hidden under MFMA). Staging is
// issue-early/write-late (T14): chunk ch+1 f32 loads issue before chunk ch's
// MFMAs, reg->LDS pack after, one __syncthreads per chunk. LDS B writes are
// 2-bit XOR-swizzled (slot c^(u&3)) so 64B-stride writes are 2-way (free) and
// fragment reads stay conflict-free (XOR folded into per-lane read base).

typedef unsigned int uint32;
typedef __attribute__((ext_vector_type(8))) short bf16x8;   // 8 bf16 = 4 VGPR
typedef __attribute__((ext_vector_type(4))) float floatx4;  // MFMA C/D
typedef __attribute__((ext_vector_type(4))) float fx4;      // float4 w/ [] access

constexpr int D  = 512;    // output width (N)
constexpr int MB = 64;     // rows per block
constexpr int PITCH = 260; // dwords per k8-slice of s_a (256 + 4 stagger)
constexpr float EPS = 1e-5f;

__device__ inline uint32 pack2(float a, float b) {
    // RNE f32x2 -> bf16x2 (low = a); compiler emits v_cvt_pk_bf16_f32
    __hip_bfloat162 h = __float22bfloat162_rn(make_float2(a, b));
    union { __hip_bfloat162 h2; uint32 u; } cv; cv.h2 = h;
    return cv.u;
}

__global__ __launch_bounds__(512, 2)
void topo_fused(const float* __restrict__ emb,
                const float* __restrict__ W,     // [256][512] f32
                const float* __restrict__ benc,
                const float* __restrict__ gamma,
                const float* __restrict__ beta,
                float* __restrict__ out)
{
    // A: 32 k8-slices x 64 rows x 16 B, pitch 260 dwords (1040 B stagger)
    __shared__ uint32 s_a[32 * PITCH];          // 33.3 KB
    // B: double-buffered bf16 chunk, 4 k8-slices x 512 n x 16 B = 32 KB each
    __shared__ uint32 s_b[2][4 * 512 * 4];      // 64 KB
    __shared__ float2 s_red[4][MB];             // LN partials (2 KB)

    const int t    = threadIdx.x;
    const int wv   = t >> 6;           // wave 0..7
    const int wr   = wv >> 2;          // row half
    const int wc   = wv & 3;           // col quarter
    const int lane = t & 63;
    const int q    = lane >> 4;        // quad 0..3
    const int cl   = lane & 15;
    const long row0 = (long)blockIdx.x * MB;

    // B-pack mapping: qc = k8-slice group (0..3), u = col/4 (0..127)
    const int qc = t >> 7;
    const int u  = t & 127;
    const int us = u & 3;              // XOR swizzle bits for writes

    // ---- prologue: issue chunk-0 W loads (f32 -> regs) ----
    fx4 wreg[8];
    {
        const fx4* src = (const fx4*)(W + (qc * 8) * D) + u;
        #pragma unroll
        for (int kk = 0; kk < 8; ++kk) wreg[kk] = src[kk * (D / 4)];
    }

    // ---- stage A: 64 rows x 256 cols f32 -> bf16 [k8][m][8k] ----
    #pragma unroll
    for (int p = 0; p < 4; ++p) {
        int m  = p * 16 + (t >> 5);
        int k8 = t & 31;
        const fx4* src = (const fx4*)(emb + (row0 + m) * D + k8 * 8);
        fx4 f0 = src[0], f1 = src[1];
        uint4 o;
        o.x = pack2(f0[0], f0[1]); o.y = pack2(f0[2], f0[3]);
        o.z = pack2(f1[0], f1[1]); o.w = pack2(f1[2], f1[3]);
        *(uint4*)&s_a[k8 * PITCH + m * 4] = o;
    }

    // ---- pack chunk 0 into s_b[0] (XOR-swizzled slots) ----
    {
        uint32* wbase = &s_b[0][qc * 2048 + u * 16];
        #pragma unroll
        for (int c = 0; c < 4; ++c) {       // cell col = 4u + c
            uint4 o;
            o.x = pack2(wreg[0][c], wreg[1][c]);
            o.y = pack2(wreg[2][c], wreg[3][c]);
            o.z = pack2(wreg[4][c], wreg[5][c]);
            o.w = pack2(wreg[6][c], wreg[7][c]);
            *(uint4*)&wbase[(c ^ us) * 4] = o;
        }
    }
    __syncthreads();

    floatx4 acc[2][8];                 // 64 VGPR, all indices static
    #pragma unroll
    for (int rt = 0; rt < 2; ++rt)
        #pragma unroll
        for (int n2 = 0; n2 < 8; ++n2)
            acc[rt][n2] = (floatx4){0.f, 0.f, 0.f, 0.f};

    // per-lane swizzled B read base (dwords): cell col = wc*128 + n2*16 + cl
    const int sb_off = q * 2048 + wc * 512 + (cl >> 2) * 16
                     + (((cl & 3) ^ (cl >> 2)) * 4);

    // ---- K loop: 8 chunks of k=32, dbuf B, issue-early / write-late ----
    for (int ch = 0; ch < 8; ++ch) {
        const int cur = ch & 1;
        if (ch < 7) {   // issue next chunk's f32 W loads (L2-resident)
            const fx4* src = (const fx4*)(W + ((ch + 1) * 32 + qc * 8) * D) + u;
            #pragma unroll
            for (int kk = 0; kk < 8; ++kk) wreg[kk] = src[kk * (D / 4)];
        }
        // A frags: lane holds A[m = wr*32 + rt*16 + cl][k = q*8+j]
        const uint32* sa = &s_a[(ch * 4 + q) * PITCH];
        bf16x8 af0 = *(const bf16x8*)&sa[(wr * 32 + cl) * 4];
        bf16x8 af1 = *(const bf16x8*)&sa[(wr * 32 + 16 + cl) * 4];
        const uint32* sb = &s_b[cur][sb_off];
        #pragma unroll
        for (int n2 = 0; n2 < 8; ++n2) {
            bf16x8 bf = *(const bf16x8*)&sb[n2 * 64];
            acc[0][n2] = __builtin_amdgcn_mfma_f32_16x16x32_bf16(af0, bf, acc[0][n2], 0, 0, 0);
            acc[1][n2] = __builtin_amdgcn_mfma_f32_16x16x32_bf16(af1, bf, acc[1][n2], 0, 0, 0);
        }
        if (ch < 7) {   // write-late: pack regs -> other buffer
            uint32* wbase = &s_b[cur ^ 1][qc * 2048 + u * 16];
            #pragma unroll
            for (int c = 0; c < 4; ++c) {
                uint4 o;
                o.x = pack2(wreg[0][c], wreg[1][c]);
                o.y = pack2(wreg[2][c], wreg[3][c]);
                o.z = pack2(wreg[4][c], wreg[5][c]);
                o.w = pack2(wreg[6][c], wreg[7][c]);
                *(uint4*)&wbase[(c ^ us) * 4] = o;
            }
        }
        __syncthreads();   // drains lgkm (writes visible) + vm; one/chunk
    }

    // ---- epilogue: bias + cross-wave LayerNorm + ReLU ----
    // C/D layout: col = wc*128 + n2*16 + cl, row = wr*32 + rt*16 + q*4 + reg
    float bv[8], sum[2][4], sq[2][4];
    #pragma unroll
    for (int n2 = 0; n2 < 8; ++n2) bv[n2] = benc[wc * 128 + n2 * 16 + cl];
    #pragma unroll
    for (int rt = 0; rt < 2; ++rt)
        #pragma unroll
        for (int r = 0; r < 4; ++r) { sum[rt][r] = 0.f; sq[rt][r] = 0.f; }

    #pragma unroll
    for (int n2 = 0; n2 < 8; ++n2)
        #pragma unroll
        for (int rt = 0; rt < 2; ++rt)
            #pragma unroll
            for (int r = 0; r < 4; ++r) {
                float v = acc[rt][n2][r] + bv[n2];
                acc[rt][n2][r] = v;
                sum[rt][r] += v;
                sq[rt][r] = fmaf(v, v, sq[rt][r]);
            }
    #pragma unroll
    for (int m = 1; m < 16; m <<= 1)
        #pragma unroll
        for (int rt = 0; rt < 2; ++rt)
            #pragma unroll
            for (int r = 0; r < 4; ++r) {
                sum[rt][r] += __shfl_xor(sum[rt][r], m, 64);
                sq[rt][r]  += __shfl_xor(sq[rt][r],  m, 64);
            }
    if (cl == 0) {
        #pragma unroll
        for (int rt = 0; rt < 2; ++rt)
            #pragma unroll
            for (int r = 0; r < 4; ++r)
                s_red[wc][wr * 32 + rt * 16 + q * 4 + r] = make_float2(sum[rt][r], sq[rt][r]);
    }
    __syncthreads();

    float mu[2][4], inv[2][4];
    #pragma unroll
    for (int rt = 0; rt < 2; ++rt)
        #pragma unroll
        for (int r = 0; r < 4; ++r) {
            int row = wr * 32 + rt * 16 + q * 4 + r;
            float s = 0.f, ss = 0.f;
            #pragma unroll
            for (int w = 0; w < 4; ++w) {
                float2 v = s_red[w][row];
                s += v.x; ss += v.y;
            }
            float m_ = s * (1.f / 512.f);
            float var = ss * (1.f / 512.f) - m_ * m_;
            mu[rt][r] = m_;
            inv[rt][r] = rsqrtf(var + EPS);
        }

    #pragma unroll
    for (int n2 = 0; n2 < 8; ++n2) {
        int c = wc * 128 + n2 * 16 + cl;
        float g = gamma[c], be = beta[c];
        #pragma unroll
        for (int rt = 0; rt < 2; ++rt) {
            float* op = out + (row0 + wr * 32 + rt * 16 + q * 4) * D + c;
            #pragma unroll
            for (int r = 0; r < 4; ++r) {
                float v = (acc[rt][n2][r] - mu[rt][r]) * inv[rt][r] * g + be;
                op[r * D] = fmaxf(v, 0.f);
            }
        }
    }
}

extern "C" void kernel_launch(void* const* d_in, const int* in_sizes, int n_in,
                              void* d_out, int out_size, void* d_ws, size_t ws_size,
                              hipStream_t stream) {
    // inputs: embeddings, W_proj, b_proj, W_enc, b_enc, ln_gamma, ln_beta
    const float* emb   = (const float*)d_in[0];
    const float* Wenc  = (const float*)d_in[3];
    const float* benc  = (const float*)d_in[4];
    const float* gamma = (const float*)d_in[5];
    const float* beta  = (const float*)d_in[6];
    float* outp = (float*)d_out;
    (void)d_ws; (void)ws_size;             // workspace intentionally unused

    const int rows = in_sizes[0] / D;      // 16384
    topo_fused<<<rows / MB, 512, 0, stream>>>(emb, Wenc, benc, gamma, beta, outp);
}